// Round 8
// baseline (537.531 us; speedup 1.0000x reference)
//
#include <hip/hip_runtime.h>
#include <hip/hip_bf16.h>
#include <stdint.h>

#define N_NODES 100000
#define DEG 16
#define D_IN 128
#define D_OUT 256
#define K_TOP 32
#define K_CAT 256   // concatenated K = D_IN(self) + D_IN(neigh)

typedef __attribute__((ext_vector_type(8))) short short8;
typedef __attribute__((ext_vector_type(4))) float floatx4;

__device__ __forceinline__ unsigned pack_bf16_rne(float f) {
    union { float f; unsigned u; } c; c.f = f;
    unsigned u = c.u;
    return (u + 0x7fffu + ((u >> 16) & 1u)) >> 16;   // round-to-nearest-even
}
__device__ __forceinline__ float bf16lo_to_f(unsigned lo16) {
    union { unsigned u; float f; } c; c.u = lo16 << 16; return c.f;
}

// async global->LDS, 16B per lane; LDS dest is wave-uniform base + lane*16
typedef __attribute__((address_space(1))) void as1_void;
typedef __attribute__((address_space(3))) void as3_void;
__device__ __forceinline__ void gload_lds16(const void* g, void* l) {
    __builtin_amdgcn_global_load_lds((as1_void*)g, (as3_void*)l, 16, 0, 0);
}

// ---- one destination row's gather+scatter: 16 coalesced uint2 loads (128B/row),
// then 32 ds_add_f32. Loads all batched before any atomic (MLP). ----
__device__ __forceinline__ void gather_row(const unsigned char* __restrict__ grec,
                                           float* __restrict__ arow,
                                           int c, float w, int ql, int qb) {
    uint2 vv[DEG];
    #pragma unroll
    for (int e = 0; e < DEG; ++e) {
        int col = __shfl(c, qb | e);
        vv[e] = *(const uint2*)(grec + (size_t)col * 128 + ql * 8);
    }
    #pragma unroll
    for (int e = 0; e < DEG; ++e) {
        float we = __shfl(w, qb | e);
        uint2 v = vv[e];
        atomicAdd(&arow[ v.y       & 255u], we * bf16lo_to_f(v.x & 0xffffu));
        atomicAdd(&arow[(v.y >> 8) & 255u], we * bf16lo_to_f(v.x >> 16));
    }
}

// -------- kernel 1 (merged prep): feat->bf16 | grec pack | weight pack --------
// grec[n] = 128 B lane-sliced record: 16 slices of 8 B; slice l holds entries
// 2l,2l+1: {bf16 val2l | val2l+1<<16, u8 idx2l | idx2l+1<<8, 2B pad}.
#define FEAT_BLKS 1563   // ceil(N/64)
#define PACK_BLKS 1563

__global__ __launch_bounds__(256) void k_prep(const float* __restrict__ feat,
                                              const float* __restrict__ topk_v,
                                              const int* __restrict__ topk_i,
                                              const float* __restrict__ w_self,
                                              const float* __restrict__ w_neigh,
                                              unsigned short* __restrict__ fbf,
                                              unsigned char* __restrict__ grec,
                                              unsigned short* __restrict__ bmat) {
    const int t = threadIdx.x;
    const int bid = blockIdx.x;
    if (bid < FEAT_BLKS) {
        // feat f32 -> fbf bf16, 64 rows/block, stride 128
        const int row0 = bid * 64;
        #pragma unroll
        for (int p = 0; p < 8; ++p) {
            int q = t + p * 256;             // 0..2047
            int r = q >> 5;                  // 0..63
            int c4 = (q & 31) * 4;
            if (row0 + r < N_NODES) {
                float4 f = *(const float4*)(feat + (size_t)(row0 + r) * D_IN + c4);
                uint2 pv;
                pv.x = pack_bf16_rne(f.x) | (pack_bf16_rne(f.y) << 16);
                pv.y = pack_bf16_rne(f.z) | (pack_bf16_rne(f.w) << 16);
                ((uint2*)(fbf + (size_t)(row0 + r) * D_IN))[q & 31] = pv;
            }
        }
    } else if (bid < FEAT_BLKS + PACK_BLKS) {
        // grec pack: 64 nodes/block, 4 threads/node, each handles entries [8p,8p+8)
        const int n = (bid - FEAT_BLKS) * 64 + (t >> 2);
        const int p = t & 3;
        if (n < N_NODES) {
            const float* vs = topk_v + (size_t)n * K_TOP + p * 8;
            float4 v0 = ((const float4*)vs)[0];
            float4 v1 = ((const float4*)vs)[1];
            const int* is = topk_i + (size_t)n * K_TOP + p * 8;
            int4 i0 = ((const int4*)is)[0];
            int4 i1 = ((const int4*)is)[1];
            uint4 lo, hi;
            lo.x = pack_bf16_rne(v0.x) | (pack_bf16_rne(v0.y) << 16);
            lo.y = (unsigned)i0.x | ((unsigned)i0.y << 8);
            lo.z = pack_bf16_rne(v0.z) | (pack_bf16_rne(v0.w) << 16);
            lo.w = (unsigned)i0.z | ((unsigned)i0.w << 8);
            hi.x = pack_bf16_rne(v1.x) | (pack_bf16_rne(v1.y) << 16);
            hi.y = (unsigned)i1.x | ((unsigned)i1.y << 8);
            hi.z = pack_bf16_rne(v1.z) | (pack_bf16_rne(v1.w) << 16);
            hi.w = (unsigned)i1.z | ((unsigned)i1.w << 8);
            unsigned char* rec = grec + (size_t)n * 128 + p * 32;
            *(uint4*)(rec)      = lo;
            *(uint4*)(rec + 16) = hi;
        }
    } else {
        // pack [w_self | w_neigh] -> bf16 B[256][256]
        const int o = bid - (FEAT_BLKS + PACK_BLKS);   // 0..255
        const int k = t;
        float v = (k < D_IN) ? w_self[o * D_IN + k] : w_neigh[o * D_IN + (k - D_IN)];
        bmat[o * K_CAT + k] = (unsigned short)pack_bf16_rne(v);
    }
}

// ------ kernel 2 (fused): sparse coalesced gather -> LDS scatter-agg, then GEMM -------
// Phase 1: quarter-wave per dst row (2 rows/quarter per 64-row pass). Per edge: one
// coalesced 128B record read (16 lanes x uint2), 2 ds_add_f32/lane into a [64][128]
// f32 accumulator; pack each pass to persistent XOR-swizzled bf16 Agg.
// Phase 2: verified GEMM loop (rounds 2/3/5/7): BM=128, BN=256, BK=32, 8 waves 2x4,
// swapped-operand mfma_f32_16x16x32_bf16; A = staged fbf (kt 0-3) then Agg (kt 4-7);
// NT float stores. LDS aliasing: aggf32 (32K) overlaps As[0..1]+Bs[0]; Bs[1] free ->
// kt=0 B prefetch flies during phase 1.
#define BM 128
#define BN 256
#define BK 32
#define NTA 4
#define NT  8

__global__ __launch_bounds__(512, 2) void k_fused(const float* __restrict__ csr_w,
                                                  const int* __restrict__ col_idx,
                                                  const unsigned char* __restrict__ grec,
                                                  const unsigned short* __restrict__ fbf,
                                                  const unsigned short* __restrict__ bmat,
                                                  const float* __restrict__ bias,
                                                  float* __restrict__ out) {
    __shared__ __align__(16) char smem[81920];                               // 80 KiB
    unsigned short* aggbf = (unsigned short*)smem;                           // [128][128] swizzled, 32K
    float* aggf = (float*)(smem + 32768);                                    // [64][128] f32, 32K (aliased)
    unsigned short (*As)[BM * BK] = (unsigned short (*)[BM * BK])(smem + 32768);   // 2 x 8K
    unsigned short (*Bs)[BN * BK] = (unsigned short (*)[BN * BK])(smem + 49152);   // 2 x 16K

    const int t = threadIdx.x;
    const int lane = t & 63, wave = t >> 6;
    const int l16 = lane & 15, quad = lane >> 4;
    const int row0 = blockIdx.x * BM;

    // staging geometry: wave covers 16 rows x 4x16B chunks, linear LDS
    const int a_r = wave * 16 + (lane >> 2);
    const int a_c = (lane & 3) * 8;                          // shorts
    int a_gr = row0 + a_r; if (a_gr >= N_NODES) a_gr = N_NODES - 1;   // clamp: never stored
    const unsigned short* gA  = fbf  + (size_t)a_gr * D_IN + a_c;
    const unsigned short* gB0 = bmat + (size_t)a_r        * K_CAT + a_c;
    const unsigned short* gB1 = bmat + (size_t)(a_r + 128) * K_CAT + a_c;

#define STAGE_A(buf, tt) gload_lds16(gA + (tt) * BK, &As[buf][wave * 16 * BK])
#define STAGE_B(buf, tt) do {                                                 \
        gload_lds16(gB0 + (tt) * BK, &Bs[buf][(wave * 16)       * BK]);       \
        gload_lds16(gB1 + (tt) * BK, &Bs[buf][(wave * 16 + 128) * BK]);       \
    } while (0)

    STAGE_B(1, 0);   // Bs[1] does not alias aggf32 -> safe to fly during phase 1

    // zero aggf32: 8192 floats / 512 thr = 4 float4 each
    #pragma unroll
    for (int p = 0; p < 4; ++p)
        *(floatx4*)&aggf[(t + p * 512) * 4] = (floatx4){0.f, 0.f, 0.f, 0.f};
    __syncthreads();

    // ---- phase 1: two 64-row passes; quarter qg owns local rows 2qg, 2qg+1 ----
    const int ql = lane & 15, qb = lane & 48;
    const int qg = wave * 4 + (lane >> 4);                   // 0..31
    #pragma unroll 1
    for (int pass = 0; pass < 2; ++pass) {
        const int rg = row0 + pass * 64 + qg * 2;            // global row, s=0
        int   c0e = 0, c1e = 0; float w0e = 0.f, w1e = 0.f;
        if (rg < N_NODES) {
            c0e = __builtin_nontemporal_load(col_idx + (size_t)rg * DEG + ql);
            w0e = __builtin_nontemporal_load(csr_w   + (size_t)rg * DEG + ql);
        }
        if (rg + 1 < N_NODES) {
            c1e = __builtin_nontemporal_load(col_idx + (size_t)(rg + 1) * DEG + ql);
            w1e = __builtin_nontemporal_load(csr_w   + (size_t)(rg + 1) * DEG + ql);
        }
        gather_row(grec, aggf + (qg * 2)     * D_IN, c0e, w0e, ql, qb);
        gather_row(grec, aggf + (qg * 2 + 1) * D_IN, c1e, w1e, ql, qb);
        __syncthreads();

        // pack aggf -> aggbf rows [pass*64, pass*64+64), XOR-swizzled; re-zero for pass 0
        #pragma unroll
        for (int s = 0; s < 8; ++s) {
            int d  = s * 512 + t;            // dword 0..4095
            int lr = d >> 6;                 // 0..63
            int c2 = (d & 63) * 2;
            float2 v = *(const float2*)&aggf[lr * D_IN + c2];
            int R = pass * 64 + lr;
            *(unsigned*)&aggbf[R * D_IN + (c2 ^ ((R & 7) << 3))] =
                pack_bf16_rne(v.x) | (pack_bf16_rne(v.y) << 16);
            if (pass == 0) *(float2*)&aggf[lr * D_IN + c2] = make_float2(0.f, 0.f);
        }
        __syncthreads();   // pack reads of aggf complete before STAGE_A overwrites it
    }

    // aggf32 dead from here; As/Bs[0] regions now usable
    STAGE_A(0, 0);

    floatx4 acc[4][4];
    #pragma unroll
    for (int i = 0; i < 4; ++i)
        #pragma unroll
        for (int j = 0; j < 4; ++j)
            acc[i][j] = (floatx4){0.f, 0.f, 0.f, 0.f};

    __syncthreads();   // drains vmcnt: As[0]/Bs[1] staged, aggbf visible

    // ---- phase 2: GEMM K-loop (B read buffer = cur^1 so kt0 uses early Bs[1]) ----
    const int wr = wave >> 2, wc = wave & 3;                 // 2x4 wave grid, 64x64 each
    #pragma unroll
    for (int tt = 0; tt < NT; ++tt) {
        const int cur = tt & 1;
        if (tt + 1 < NTA) STAGE_A(cur ^ 1, tt + 1);          // prefetch next A (fbf half)
        if (tt + 1 < NT)  STAGE_B(cur, tt + 1);              // prefetch next B (into read^1)

        short8 afr[4], bfr[4];
        if (tt < NTA) {
            #pragma unroll
            for (int i = 0; i < 4; ++i)
                afr[i] = *(const short8*)&As[cur][(wr * 64 + i * 16 + l16) * BK + quad * 8];
        } else {
            const int c0 = (tt - NTA) * 32 + quad * 8;
            #pragma unroll
            for (int i = 0; i < 4; ++i) {
                const int m = wr * 64 + i * 16 + l16;
                afr[i] = *(const short8*)&aggbf[m * 128 + (c0 ^ ((m & 7) << 3))];
            }
        }
        #pragma unroll
        for (int j = 0; j < 4; ++j)
            bfr[j] = *(const short8*)&Bs[cur ^ 1][(wc * 64 + j * 16 + l16) * BK + quad * 8];

        #pragma unroll
        for (int i = 0; i < 4; ++i)
            #pragma unroll
            for (int j = 0; j < 4; ++j)   // swapped: out-rows <- afr lanes, out-cols <- bfr regs
                acc[i][j] = __builtin_amdgcn_mfma_f32_16x16x32_bf16(bfr[j], afr[i], acc[i][j], 0, 0, 0);

        if (tt + 1 < NT) __syncthreads();
    }

    // epilogue: lane holds row m = l16 (+16i+64wr), cols quad*4..+3 (+16j+64wc)
    // nontemporal floatx4 stores (write-once stream stays out of L2/L3)
    #pragma unroll
    for (int j = 0; j < 4; ++j) {
        const int cg = wc * 64 + j * 16 + quad * 4;
        const floatx4 bv = *(const floatx4*)&bias[cg];
        #pragma unroll
        for (int i = 0; i < 4; ++i) {
            const int gr = row0 + wr * 64 + i * 16 + l16;
            if (gr < N_NODES) {
                floatx4 v = acc[i][j] + bv;
                __builtin_nontemporal_store(v, (floatx4*)(out + (size_t)gr * D_OUT + cg));
            }
        }
    }
#undef STAGE_A
#undef STAGE_B
}

extern "C" void kernel_launch(void* const* d_in, const int* in_sizes, int n_in,
                              void* d_out, int out_size, void* d_ws, size_t ws_size,
                              hipStream_t stream) {
    const float* feat    = (const float*)d_in[0];
    const float* topk_v  = (const float*)d_in[1];
    const float* csr_w   = (const float*)d_in[2];
    const float* w_neigh = (const float*)d_in[3];
    const float* w_self  = (const float*)d_in[4];
    const float* b_self  = (const float*)d_in[5];
    const int*   topk_i  = (const int*)d_in[6];
    // d_in[7] = indptr (fixed degree 16, unused), d_in[8] = indices
    const int*   indices = (const int*)d_in[8];
    float* out = (float*)d_out;

    // workspace: fbf bf16[N*128] (25.6MB) | grec u8[N*128] (12.8MB) | bmat bf16[256*256]
    unsigned char* base = (unsigned char*)d_ws;
    unsigned short* fbf  = (unsigned short*)base;
    unsigned char*  grec = base + (size_t)N_NODES * D_IN * 2;
    unsigned short* bmat = (unsigned short*)(grec + (size_t)N_NODES * 128);

    k_prep<<<dim3(FEAT_BLKS + PACK_BLKS + 256), dim3(256), 0, stream>>>(
        feat, topk_v, topk_i, w_self, w_neigh, fbf, grec, bmat);
    k_fused<<<dim3((N_NODES + BM - 1) / BM), dim3(512), 0, stream>>>(
        csr_w, indices, grec, fbf, bmat, b_self, out);
}

// Round 9
// 271.074 us; speedup vs baseline: 1.9830x; 1.9830x over previous
//
#include <hip/hip_runtime.h>
#include <hip/hip_bf16.h>
#include <stdint.h>

#define N_NODES 100000
#define DEG 16
#define D_IN 128
#define D_OUT 256
#define K_TOP 32
#define K_CAT 256   // concatenated K = D_IN(self) + D_IN(neigh)

typedef __attribute__((ext_vector_type(8))) short short8;
typedef __attribute__((ext_vector_type(4))) float floatx4;

__device__ __forceinline__ unsigned pack_bf16_rne(float f) {
    union { float f; unsigned u; } c; c.f = f;
    unsigned u = c.u;
    return (u + 0x7fffu + ((u >> 16) & 1u)) >> 16;   // round-to-nearest-even
}
__device__ __forceinline__ float bf16lo_to_f(unsigned lo16) {
    union { unsigned u; float f; } c; c.u = lo16 << 16; return c.f;
}

// async global->LDS, 16B per lane; LDS dest is wave-uniform base + lane*16
typedef __attribute__((address_space(1))) void as1_void;
typedef __attribute__((address_space(3))) void as3_void;
__device__ __forceinline__ void gload_lds16(const void* g, void* l) {
    __builtin_amdgcn_global_load_lds((as1_void*)g, (as3_void*)l, 16, 0, 0);
}

// ---------------- kernel 1: pack [w_self | w_neigh] -> bf16 B[256][256] ----------------
__global__ __launch_bounds__(256) void k_packw(const float* __restrict__ w_self,
                                               const float* __restrict__ w_neigh,
                                               unsigned short* __restrict__ bmat) {
    int o = blockIdx.x;      // 0..255 output channel
    int k = threadIdx.x;     // 0..255 concat-K
    float v = (k < D_IN) ? w_self[o * D_IN + k] : w_neigh[o * D_IN + (k - D_IN)];
    bmat[o * K_CAT + k] = (unsigned short)pack_bf16_rne(v);
}

// ------------- kernel 2: densify via LDS ds_add_f32 scatter + feat->bf16 ---------------
// Writes xbf[N][128] (dense top-k features) and fbf[N][128] (feat as bf16, stride 128).
#define DROWS 64
__global__ __launch_bounds__(256) void k_densify(const float* __restrict__ topk_v,
                                                 const int* __restrict__ topk_i,
                                                 const float* __restrict__ feat,
                                                 unsigned short* __restrict__ xbf,
                                                 unsigned short* __restrict__ fbf) {
    __shared__ float sx[DROWS * D_IN];   // 32 KiB
    const int t = threadIdx.x;
    const int row0 = blockIdx.x * DROWS;

    // zero LDS: 8192 floats / 256 thr = 8 float4 per thread
    #pragma unroll
    for (int p = 0; p < 8; ++p)
        *(floatx4*)&sx[(t + p * 256) * 4] = (floatx4){0.f, 0.f, 0.f, 0.f};
    __syncthreads();

    // scatter: 64 rows x 32 pairs = 2048 pairs, 8 per thread, coalesced reads
    const size_t tbase = (size_t)row0 * K_TOP;
    #pragma unroll
    for (int p = 0; p < 8; ++p) {
        int q = t + p * 256;             // 0..2047
        int r = q >> 5;                  // 0..63
        if (row0 + r < N_NODES) {
            int   ci = topk_i[tbase + q];
            float cv = topk_v[tbase + q];
            atomicAdd(&sx[r * D_IN + ci], cv);   // ds_add_f32, no return
        }
    }
    __syncthreads();

    // pack x -> bf16, coalesced: 4096 dwords, 16 per thread
    #pragma unroll
    for (int p = 0; p < 16; ++p) {
        int d = t + p * 256;             // dword index 0..4095
        int r = d >> 6;                  // 0..63
        int c2 = (d & 63) * 2;
        if (row0 + r < N_NODES) {
            float2 v = *(const float2*)&sx[r * D_IN + c2];
            ((unsigned*)(xbf + (size_t)(row0 + r) * D_IN))[d & 63] =
                pack_bf16_rne(v.x) | (pack_bf16_rne(v.y) << 16);
        }
    }

    // feat -> bf16 into fbf (stride 128): 2048 float4, 8 per thread
    #pragma unroll
    for (int p = 0; p < 8; ++p) {
        int q = t + p * 256;             // 0..2047
        int r = q >> 5;                  // 0..63
        int c4 = (q & 31) * 4;
        if (row0 + r < N_NODES) {
            float4 f = *(const float4*)(feat + (size_t)(row0 + r) * D_IN + c4);
            uint2 pk;
            pk.x = pack_bf16_rne(f.x) | (pack_bf16_rne(f.y) << 16);
            pk.y = pack_bf16_rne(f.z) | (pack_bf16_rne(f.w) << 16);
            ((uint2*)(fbf + (size_t)(row0 + r) * D_IN))[q & 31] = pk;
        }
    }
}

// ------ kernel 3 (fused): per-block SpMM gather -> LDS agg, then GEMM over K=256 -------
// out[N][256] = [fbf | agg] @ B[256][256]^T + bias.  (Round-7 structure; phase 1 now
// software-pipelined.)
// Phase 1: quarter-wave per dst row, 4 passes. NEW: all 4 passes' col/weight hoisted
// up-front; gathers ping-pong in 8-edge sub-passes (vva/vvb) so the next 8 loads are
// in flight while the current 8 feed FMAs — sustained MLP instead of burst+drain.
// Phase 2: BM=128, BN=256 (A read once), BK=32, 8 waves (2x4), swapped-operand
// mfma_f32_16x16x32_bf16; A = staged fbf (kt 0-3) then LDS Agg (kt 4-7); NT stores.
#define BM 128
#define BN 256
#define BK 32
#define NTA 4   // K-steps covered by fbf
#define NT  8

__global__ __launch_bounds__(512, 2) void k_fused(const float* __restrict__ csr_w,
                                                  const int* __restrict__ col_idx,
                                                  const unsigned short* __restrict__ xbf,
                                                  const unsigned short* __restrict__ fbf,
                                                  const unsigned short* __restrict__ bmat,
                                                  const float* __restrict__ bias,
                                                  float* __restrict__ out) {
    __shared__ __align__(16) unsigned short Agg[BM * 128];     // 32 KiB, swizzled
    __shared__ __align__(16) unsigned short As[2][BM * BK];    // 16 KiB
    __shared__ __align__(16) unsigned short Bs[2][BN * BK];    // 32 KiB
    const int t    = threadIdx.x;
    const int lane = t & 63, wave = t >> 6;
    const int l16  = lane & 15, quad = lane >> 4;
    const int row0 = blockIdx.x * BM;

    // staging geometry: each wave's 64 lanes cover 16 rows x 4x16B chunks (linear LDS)
    const int a_r = wave * 16 + (lane >> 2);
    const int a_c = (lane & 3) * 8;                          // shorts
    int a_gr = row0 + a_r; if (a_gr >= N_NODES) a_gr = N_NODES - 1;  // clamp: garbage
    const unsigned short* gA  = fbf  + (size_t)a_gr * D_IN + a_c;    // rows never stored
    const unsigned short* gB0 = bmat + (size_t)a_r        * K_CAT + a_c;
    const unsigned short* gB1 = bmat + (size_t)(a_r + 128) * K_CAT + a_c;

#define STAGE_A(buf, tt) gload_lds16(gA + (tt) * BK, &As[buf][wave * 16 * BK])
#define STAGE_B(buf, tt) do {                                                 \
        gload_lds16(gB0 + (tt) * BK, &Bs[buf][(wave * 16)       * BK]);       \
        gload_lds16(gB1 + (tt) * BK, &Bs[buf][(wave * 16 + 128) * BK]);       \
    } while (0)

    // issue first K-step staging now; it flies during the gather phase
    STAGE_A(0, 0);
    STAGE_B(0, 0);

    // ---- phase 1: pipelined gather-aggregate, quarter-wave per row, 4 passes ----
    const int ql = lane & 15, qb = lane & 48;
    const int qrow = wave * 4 + (lane >> 4);                 // quarter's row within a pass

    // hoist all 4 passes' col/weight (coalesced, guarded)
    int cc[4]; float ww[4];
    #pragma unroll
    for (int p = 0; p < 4; ++p) {
        const int gr = row0 + p * 32 + qrow;
        cc[p] = 0; ww[p] = 0.f;
        if (gr < N_NODES) {
            cc[p] = __builtin_nontemporal_load(col_idx + (size_t)gr * DEG + ql);
            ww[p] = __builtin_nontemporal_load(csr_w   + (size_t)gr * DEG + ql);
        }
    }

    uint4 vva[8], vvb[8];
    // prime: sub-pass 0 = pass 0, edges 0..7
    #pragma unroll
    for (int e = 0; e < 8; ++e) {
        int col = __shfl(cc[0], qb | e);
        vva[e] = *(const uint4*)(xbf + (size_t)col * D_IN + ql * 8);
    }
    float a[8] = {0.f, 0.f, 0.f, 0.f, 0.f, 0.f, 0.f, 0.f};

    #pragma unroll
    for (int s = 0; s < 8; ++s) {                            // 8 sub-passes (4 passes x 2)
        const int p  = s >> 1;
        const int e0 = (s & 1) * 8;
        // issue next sub-pass's 8 gathers into the other buffer (static selection)
        if (s < 7) {
            const int np  = (s + 1) >> 1;
            const int ne0 = ((s + 1) & 1) * 8;
            #pragma unroll
            for (int e = 0; e < 8; ++e) {
                int col = __shfl(cc[np], qb | (ne0 + e));
                if (s & 1) vva[e] = *(const uint4*)(xbf + (size_t)col * D_IN + ql * 8);
                else       vvb[e] = *(const uint4*)(xbf + (size_t)col * D_IN + ql * 8);
            }
        }
        // consume current buffer
        #pragma unroll
        for (int e = 0; e < 8; ++e) {
            float we = __shfl(ww[p], qb | (e0 + e));
            uint4 v = (s & 1) ? vvb[e] : vva[e];
            a[0] += we * bf16lo_to_f(v.x & 0xffffu);
            a[1] += we * bf16lo_to_f(v.x >> 16);
            a[2] += we * bf16lo_to_f(v.y & 0xffffu);
            a[3] += we * bf16lo_to_f(v.y >> 16);
            a[4] += we * bf16lo_to_f(v.z & 0xffffu);
            a[5] += we * bf16lo_to_f(v.z >> 16);
            a[6] += we * bf16lo_to_f(v.w & 0xffffu);
            a[7] += we * bf16lo_to_f(v.w >> 16);
        }
        if (s & 1) {
            // end of pass p: pack this row to Agg (XOR-swizzled), reset accumulator
            const int r = p * 32 + qrow;
            uint4 pk;
            pk.x = pack_bf16_rne(a[0]) | (pack_bf16_rne(a[1]) << 16);
            pk.y = pack_bf16_rne(a[2]) | (pack_bf16_rne(a[3]) << 16);
            pk.z = pack_bf16_rne(a[4]) | (pack_bf16_rne(a[5]) << 16);
            pk.w = pack_bf16_rne(a[6]) | (pack_bf16_rne(a[7]) << 16);
            *(uint4*)&Agg[r * 128 + ((ql * 8) ^ ((r & 7) << 3))] = pk;
            #pragma unroll
            for (int z = 0; z < 8; ++z) a[z] = 0.f;
        }
    }

    // ---- phase 2: GEMM K-loop ----
    const int wr = wave >> 2, wc = wave & 3;                 // 2x4 wave grid, 64x64 each
    floatx4 acc[4][4];
    #pragma unroll
    for (int i = 0; i < 4; ++i)
        #pragma unroll
        for (int j = 0; j < 4; ++j)
            acc[i][j] = (floatx4){0.f, 0.f, 0.f, 0.f};

    __syncthreads();   // drains vmcnt(0): buf0 staged + Agg writes visible

    #pragma unroll
    for (int tt = 0; tt < NT; ++tt) {
        const int cur = tt & 1;
        if (tt + 1 < NTA) STAGE_A(cur ^ 1, tt + 1);          // prefetch next A (fbf half)
        if (tt + 1 < NT)  STAGE_B(cur ^ 1, tt + 1);          // prefetch next B

        short8 afr[4], bfr[4];
        if (tt < NTA) {
            #pragma unroll
            for (int i = 0; i < 4; ++i)
                afr[i] = *(const short8*)&As[cur][(wr * 64 + i * 16 + l16) * BK + quad * 8];
        } else {
            const int c0 = (tt - NTA) * 32 + quad * 8;
            #pragma unroll
            for (int i = 0; i < 4; ++i) {
                const int m = wr * 64 + i * 16 + l16;
                afr[i] = *(const short8*)&Agg[m * 128 + (c0 ^ ((m & 7) << 3))];
            }
        }
        #pragma unroll
        for (int j = 0; j < 4; ++j)
            bfr[j] = *(const short8*)&Bs[cur][(wc * 64 + j * 16 + l16) * BK + quad * 8];

        #pragma unroll
        for (int i = 0; i < 4; ++i)
            #pragma unroll
            for (int j = 0; j < 4; ++j)   // swapped: out-rows <- afr lanes, out-cols <- bfr regs
                acc[i][j] = __builtin_amdgcn_mfma_f32_16x16x32_bf16(bfr[j], afr[i], acc[i][j], 0, 0, 0);

        if (tt + 1 < NT) __syncthreads();
    }

    // epilogue: lane holds row m = l16 (+16i+64wr), cols quad*4..+3 (+16j+64wc)
    // nontemporal floatx4 stores (write-once stream stays out of L2/L3)
    #pragma unroll
    for (int j = 0; j < 4; ++j) {
        const int cg = wc * 64 + j * 16 + quad * 4;
        const floatx4 bv = *(const floatx4*)&bias[cg];
        #pragma unroll
        for (int i = 0; i < 4; ++i) {
            const int gr = row0 + wr * 64 + i * 16 + l16;
            if (gr < N_NODES) {
                floatx4 v = acc[i][j] + bv;
                __builtin_nontemporal_store(v, (floatx4*)(out + (size_t)gr * D_OUT + cg));
            }
        }
    }
#undef STAGE_A
#undef STAGE_B
}

extern "C" void kernel_launch(void* const* d_in, const int* in_sizes, int n_in,
                              void* d_out, int out_size, void* d_ws, size_t ws_size,
                              hipStream_t stream) {
    const float* feat    = (const float*)d_in[0];
    const float* topk_v  = (const float*)d_in[1];
    const float* csr_w   = (const float*)d_in[2];
    const float* w_neigh = (const float*)d_in[3];
    const float* w_self  = (const float*)d_in[4];
    const float* b_self  = (const float*)d_in[5];
    const int*   topk_i  = (const int*)d_in[6];
    // d_in[7] = indptr (fixed degree 16, unused), d_in[8] = indices
    const int*   indices = (const int*)d_in[8];
    float* out = (float*)d_out;

    // workspace layout (bf16): x[N*128] | f[N*128] | B[256*256]  (~51.4 MB)
    unsigned short* xbf  = (unsigned short*)d_ws;
    unsigned short* fbf  = xbf + (size_t)N_NODES * D_IN;
    unsigned short* bmat = fbf + (size_t)N_NODES * D_IN;

    k_packw<<<dim3(256), dim3(256), 0, stream>>>(w_self, w_neigh, bmat);
    k_densify<<<dim3((N_NODES + DROWS - 1) / DROWS), dim3(256), 0, stream>>>(topk_v, topk_i, feat, xbf, fbf);
    k_fused<<<dim3((N_NODES + BM - 1) / BM), dim3(512), 0, stream>>>(
        csr_w, indices, xbf, fbf, bmat, b_self, out);
}